// Round 2
// baseline (1117.070 us; speedup 1.0000x reference)
//
#include <hip/hip_runtime.h>

// LSTM: SEQ=4096, BATCH=4096, IN=2, HID=8, fp32.
// R8 = dual-chain ILP: 32 lanes/batch layout (lane = g*8+u), but each lane now
// carries TWO independent batch recurrences (adjacent batches bA, bA+1) fully
// interleaved in one instruction stream. 1024 waves = 1 wave/SIMD.
//  - weights (W0..W7, wx, bias, tm, addc) are lane-functions -> shared by both
//    chains: zero duplication of the weight set
//  - both chains' x inputs = one float4 load per step (adjacent batches)
//  - DPP gather tree is depth-2 (h^7 via row_half_mirror, then ^1/^2/^3
//    quad_perms of h and h^7) instead of the R7 serial 7-hop chain
//  - update_dpp with bound_ctrl=1 -> single v_mov_b32_dpp, no tied-old copy
//  - chain B's matvec sits between chain A's bpermute issue and its wait
//  - numerics identical to R6/R7: weights pre-scaled by -log2e (-2log2e for
//    g~), c in scaled space c' = -2*log2e*c, sigmoid/tanh via exp2+rcp only

#define SEQ   4096
#define BATCH 4096
#define PF    8

#define DPP_X1   0xB1  // quad_perm [1,0,3,2] : lane ^ 1
#define DPP_X2   0x4E  // quad_perm [2,3,0,1] : lane ^ 2
#define DPP_X3   0x1B  // quad_perm [3,2,1,0] : lane ^ 3
#define DPP_HMIR 0x141 // row_half_mirror     : lane ^ 7 (within 8-lane group)

template<int CTRL>
__device__ __forceinline__ float rot(float v) {
    int i = __builtin_bit_cast(int, v);
    // bound_ctrl=1: invalid lanes read 0 (none here) -> old operand dead,
    // compiler emits a single untied v_mov_b32_dpp
    int r = __builtin_amdgcn_update_dpp(0, i, CTRL, 0xf, 0xf, true);
    return __builtin_bit_cast(float, r);
}

__device__ __forceinline__ float bperm(int byteaddr, float v) {
    int r = __builtin_amdgcn_ds_bpermute(byteaddr, __builtin_bit_cast(int, v));
    return __builtin_bit_cast(float, r);
}

__global__ __launch_bounds__(256, 1) void lstm_kernel(
    const float* __restrict__ x,    // (SEQ, BATCH, 2)
    const float* __restrict__ h0,   // (1, BATCH, 8)
    const float* __restrict__ c0,   // (1, BATCH, 8)
    const float* __restrict__ Wih,  // (32, 2)
    const float* __restrict__ Whh,  // (32, 8)
    const float* __restrict__ bih,  // (32)
    const float* __restrict__ bhh,  // (32)
    float* __restrict__ out)        // (1, BATCH, 8)
{
    const int tid = threadIdx.x;
    const int l32 = tid & 31;        // lane within 32-lane group
    const int g   = l32 >> 3;        // gate: 0=i 1=f 2=g~ 3=o
    const int u   = l32 & 7;         // unit 0..7
    const int bA  = blockIdx.x * 16 + (tid >> 5) * 2;  // even batch
    const int row = g * 8 + u;       // gate row in (32,·) weight matrices

    const float L2E = 1.4426950408889634f;
    const float cs  = -2.0f * L2E;
    const float smul = (g == 2) ? cs : -L2E;
    // finalize act = r*tm + addc per gate:
    //  i: tm=-2*L2E (emit -2L2E*sigma for scaled-c recurrence), addc=0
    //  f: tm=1       g~: tm=2, addc=-1 (tanh)       o: tm=2 (2*sigma)
    const float tm   = (g == 0) ? cs : ((g >= 2) ? 2.0f : 1.0f);
    const float addc = (g == 2) ? -1.0f : 0.0f;

    // Whh row, direct xor order (tree produces h^k in order 0..7), PRE-SCALED
    const float* wr = Whh + row * 8;
    const float W0 = wr[u ^ 0] * smul, W1 = wr[u ^ 1] * smul;
    const float W2 = wr[u ^ 2] * smul, W3 = wr[u ^ 3] * smul;
    const float W4 = wr[u ^ 4] * smul, W5 = wr[u ^ 5] * smul;
    const float W6 = wr[u ^ 6] * smul, W7 = wr[u ^ 7] * smul;
    const float wx0 = Wih[2 * row] * smul, wx1 = Wih[2 * row + 1] * smul;
    const float bias = (bih[row] + bhh[row]) * smul;

    // ds_bpermute byte addresses of the 4 gate owners (within own half-wave)
    const int abase = ((tid & 32) | u) << 2;
    const int ai = abase, af = abase + 32, ag = abase + 64, ao = abase + 96;

    // two independent recurrences per lane (c in scaled space)
    float cA = c0[bA * 8 + u] * cs,     hA = h0[bA * 8 + u];
    float cB = c0[bA * 8 + 8 + u] * cs, hB = h0[bA * 8 + 8 + u];

    // x viewed as float4: (SEQ, BATCH/2); one load feeds both chains
    const float4* __restrict__ xp4 = (const float4*)x;
    const int xcol = bA >> 1;
    float4 xb[PF];
#pragma unroll
    for (int p = 0; p < PF; ++p) xb[p] = xp4[p * (BATCH / 2) + xcol];

    for (int s = 0; s < SEQ; s += PF) {
#pragma unroll
        for (int p = 0; p < PF; ++p) {
            const float4 xc = xb[p];
            const int sn = (s + p + PF) & (SEQ - 1);   // uniform wrap
            xb[p] = xp4[sn * (BATCH / 2) + xcol];

            // ================= chain A: matvec (depth-2 DPP tree) ========
            const float mA  = rot<DPP_HMIR>(hA);       // h^7
            const float a1A = rot<DPP_X1>(hA);         // h^1
            const float a2A = rot<DPP_X2>(hA);         // h^2
            const float a3A = rot<DPP_X3>(hA);         // h^3
            const float a4A = rot<DPP_X3>(mA);         // h^4
            const float a5A = rot<DPP_X2>(mA);         // h^5
            const float a6A = rot<DPP_X1>(mA);         // h^6
            float sA0 = __builtin_fmaf(xc.x, wx0, bias);
            float sA1 = xc.y * wx1;
            sA0 = __builtin_fmaf(hA,  W0, sA0);  sA1 = __builtin_fmaf(a1A, W1, sA1);
            sA0 = __builtin_fmaf(a2A, W2, sA0);  sA1 = __builtin_fmaf(a3A, W3, sA1);
            sA0 = __builtin_fmaf(a4A, W4, sA0);  sA1 = __builtin_fmaf(a5A, W5, sA1);
            sA0 = __builtin_fmaf(a6A, W6, sA0);  sA1 = __builtin_fmaf(mA,  W7, sA1);
            const float preA = sA0 + sA1;              // already scaled
            const float eA   = __builtin_amdgcn_exp2f(preA);
            const float rA   = __builtin_amdgcn_rcpf(eA + 1.0f);
            const float actA = __builtin_fmaf(rA, tm, addc);
            const float giA  = bperm(ai, actA);
            const float gfA  = bperm(af, actA);
            const float ggA  = bperm(ag, actA);
            const float goA  = bperm(ao, actA);

            // ================= chain B: matvec (covers A's bperm wait) ===
            const float mB  = rot<DPP_HMIR>(hB);
            const float b1B = rot<DPP_X1>(hB);
            const float b2B = rot<DPP_X2>(hB);
            const float b3B = rot<DPP_X3>(hB);
            const float b4B = rot<DPP_X3>(mB);
            const float b5B = rot<DPP_X2>(mB);
            const float b6B = rot<DPP_X1>(mB);
            float sB0 = __builtin_fmaf(xc.z, wx0, bias);
            float sB1 = xc.w * wx1;
            sB0 = __builtin_fmaf(hB,  W0, sB0);  sB1 = __builtin_fmaf(b1B, W1, sB1);
            sB0 = __builtin_fmaf(b2B, W2, sB0);  sB1 = __builtin_fmaf(b3B, W3, sB1);
            sB0 = __builtin_fmaf(b4B, W4, sB0);  sB1 = __builtin_fmaf(b5B, W5, sB1);
            sB0 = __builtin_fmaf(b6B, W6, sB0);  sB1 = __builtin_fmaf(mB,  W7, sB1);
            const float preB = sB0 + sB1;
            const float eB   = __builtin_amdgcn_exp2f(preB);
            const float rB   = __builtin_amdgcn_rcpf(eB + 1.0f);
            const float actB = __builtin_fmaf(rB, tm, addc);
            const float giB  = bperm(ai, actB);
            const float gfB  = bperm(af, actB);
            const float ggB  = bperm(ag, actB);
            const float goB  = bperm(ao, actB);

            // ================= chain A: c/h update (all lanes, convergent)
            cA = __builtin_fmaf(gfA, cA, giA * ggA);
            const float e2A = __builtin_amdgcn_exp2f(cA);
            const float r2A = __builtin_amdgcn_rcpf(e2A + 1.0f);
            hA = __builtin_fmaf(goA, r2A, goA * -0.5f);  // h = 2sig*r - sig

            // ================= chain B: c/h update ========================
            cB = __builtin_fmaf(gfB, cB, giB * ggB);
            const float e2B = __builtin_amdgcn_exp2f(cB);
            const float r2B = __builtin_amdgcn_rcpf(e2B + 1.0f);
            hB = __builtin_fmaf(goB, r2B, goB * -0.5f);
        }
    }

    if (g == 0) {
        out[bA * 8 + u]     = hA;
        out[bA * 8 + 8 + u] = hB;
    }
}

extern "C" void kernel_launch(void* const* d_in, const int* in_sizes, int n_in,
                              void* d_out, int out_size, void* d_ws, size_t ws_size,
                              hipStream_t stream) {
    const float* x   = (const float*)d_in[0];
    const float* h0  = (const float*)d_in[1];
    const float* c0  = (const float*)d_in[2];
    const float* Wih = (const float*)d_in[3];
    const float* Whh = (const float*)d_in[4];
    const float* bih = (const float*)d_in[5];
    const float* bhh = (const float*)d_in[6];
    float* out = (float*)d_out;

    dim3 grid(BATCH / 16);   // 256 blocks, 1 per CU
    dim3 block(256);         // 4 waves x (2 half-waves x 2 chains) = 16 batches
    hipLaunchKernelGGL(lstm_kernel, grid, block, 0, stream,
                       x, h0, c0, Wih, Whh, bih, bhh, out);
}

// Round 3
// 755.923 us; speedup vs baseline: 1.4778x; 1.4778x over previous
//
#include <hip/hip_runtime.h>

// LSTM: SEQ=4096, BATCH=4096, IN=2, HID=8, fp32.
// R9 = gate-exchange elimination. 16 lanes/batch: lane l16 = hf*8 + u.
//   half0 (hf=0, lanes 0-7 of each 16-row) owns gate rows (i, g~) of unit u
//   half1 (hf=1, lanes 8-15)               owns gate rows (f, o)  of unit u
// Per step: 7-DPP h-gather (shared by both rows), two independent 10-term
// dots (ILP-2), two activation chains, i*g~ computed LOCALLY on half0,
// then exactly 3 bank-masked row_ror:8 DPPs distribute {gf, go2, i*g~} so
// ALL lanes run the c/h update validly -> h replicated by construction.
// No ds_bpermute, no gate-broadcast DPP layer, no exec masking, no final
// h re-broadcast. 1024 waves = 1/SIMD, 4 batches/wave, zero redundancy.
// Numerics identical to R6-R8: weights pre-scaled by -log2e (-2log2e for
// g~), c in scaled space c' = -2*log2e*c, sigmoid/tanh via exp2+rcp only.

#define SEQ   4096
#define BATCH 4096
#define PF    8

#define DPP_X1   0xB1  // quad_perm [1,0,3,2] : lane ^ 1
#define DPP_X2   0x4E  // quad_perm [2,3,0,1] : lane ^ 2
#define DPP_X3   0x1B  // quad_perm [3,2,1,0] : lane ^ 3
#define DPP_HMIR 0x141 // row_half_mirror     : lane ^ 7 (within 8-lane half)
#define DPP_ROR8 0x128 // row_ror:8           : lane ^ 8 (within 16-lane row)

template<int CTRL>
__device__ __forceinline__ float rot(float v) {
    int i = __builtin_bit_cast(int, v);
    int r = __builtin_amdgcn_update_dpp(0, i, CTRL, 0xf, 0xf, true);
    return __builtin_bit_cast(float, r);
}

// ror8 with bank-masked merge: lanes in enabled BANKS receive src[l^8],
// disabled banks keep 'oldv'. banks 0,1 = lanes 0-7 (half0); 2,3 = 8-15.
template<int BANKS>
__device__ __forceinline__ float ror8_keep(float oldv, float src) {
    int o = __builtin_bit_cast(int, oldv);
    int s = __builtin_bit_cast(int, src);
    int r = __builtin_amdgcn_update_dpp(o, s, DPP_ROR8, 0xf, BANKS, false);
    return __builtin_bit_cast(float, r);
}

__global__ __launch_bounds__(256, 1) void lstm_kernel(
    const float* __restrict__ x,    // (SEQ, BATCH, 2)
    const float* __restrict__ h0,   // (1, BATCH, 8)
    const float* __restrict__ c0,   // (1, BATCH, 8)
    const float* __restrict__ Wih,  // (32, 2)
    const float* __restrict__ Whh,  // (32, 8)
    const float* __restrict__ bih,  // (32)
    const float* __restrict__ bhh,  // (32)
    float* __restrict__ out)        // (1, BATCH, 8)
{
    const int tid = threadIdx.x;
    const int l16 = tid & 15;
    const int u   = l16 & 7;         // unit 0..7
    const int hf  = l16 >> 3;        // 0: rows (i,g~)   1: rows (f,o)
    const int b   = blockIdx.x * 16 + (tid >> 4);

    const int row0 = hf * 8 + u;      // i-row (0..7)  or f-row (8..15)
    const int row1 = 16 + row0;       // g~-row (16..23) or o-row (24..31)

    const float L2E = 1.4426950408889634f;
    const float n2L = -2.0f * L2E;
    // pre-activation scales folded into weights:
    //   sigmoid rows (i,f,o): -L2E     tanh row (g~): -2*L2E
    const float smul0 = -L2E;
    const float smul1 = hf ? -L2E : n2L;
    // act0 = r0*tm0:        i -> -2L2E*sigma (scaled-c form)   f -> sigma
    // act1 = r1*2 + addc1:  g~ -> tanh                         o -> 2*sigma
    const float tm0   = hf ? 1.0f : n2L;
    const float addc1 = hf ? 0.0f : -1.0f;

    // weights in gather order (tree yields h^m for m=0..7), PRE-SCALED
    const float* wr0 = Whh + row0 * 8;
    const float* wr1 = Whh + row1 * 8;
    float W0[8], W1[8];
#pragma unroll
    for (int m = 0; m < 8; ++m) {
        W0[m] = wr0[u ^ m] * smul0;
        W1[m] = wr1[u ^ m] * smul1;
    }
    const float wx00 = Wih[2 * row0] * smul0, wx01 = Wih[2 * row0 + 1] * smul0;
    const float wx10 = Wih[2 * row1] * smul1, wx11 = Wih[2 * row1 + 1] * smul1;
    const float bias0 = (bih[row0] + bhh[row0]) * smul0;
    const float bias1 = (bih[row1] + bhh[row1]) * smul1;

    // state: c in scaled space c' = -2*L2E*c; maintained validly in ALL lanes
    float c = c0[b * 8 + u] * n2L;
    float h = h0[b * 8 + u];

    const float2* __restrict__ xp2 = (const float2*)x;
    float2 xb[PF];
#pragma unroll
    for (int p = 0; p < PF; ++p) xb[p] = xp2[p * BATCH + b];

    for (int s = 0; s < SEQ; s += PF) {
#pragma unroll
        for (int p = 0; p < PF; ++p) {
            const float2 xc = xb[p];
            const int sn = (s + p + PF) & (SEQ - 1);   // uniform wrap
            xb[p] = xp2[sn * BATCH + b];

            // ---- h-gather: depth-2 DPP tree within each 8-lane half
            const float h1 = rot<DPP_X1>(h);
            const float h2 = rot<DPP_X2>(h);
            const float h3 = rot<DPP_X3>(h);
            const float h7 = rot<DPP_HMIR>(h);
            const float h4 = rot<DPP_X3>(h7);
            const float h5 = rot<DPP_X2>(h7);
            const float h6 = rot<DPP_X1>(h7);

            // ---- two independent 10-term dots (ILP-2), 2 chains each
            float s00 = __builtin_fmaf(xc.x, wx00, bias0);
            float s01 = xc.y * wx01;
            float s10 = __builtin_fmaf(xc.x, wx10, bias1);
            float s11 = xc.y * wx11;
            s00 = __builtin_fmaf(h,  W0[0], s00);  s01 = __builtin_fmaf(h1, W0[1], s01);
            s10 = __builtin_fmaf(h,  W1[0], s10);  s11 = __builtin_fmaf(h1, W1[1], s11);
            s00 = __builtin_fmaf(h2, W0[2], s00);  s01 = __builtin_fmaf(h3, W0[3], s01);
            s10 = __builtin_fmaf(h2, W1[2], s10);  s11 = __builtin_fmaf(h3, W1[3], s11);
            s00 = __builtin_fmaf(h4, W0[4], s00);  s01 = __builtin_fmaf(h5, W0[5], s01);
            s10 = __builtin_fmaf(h4, W1[4], s10);  s11 = __builtin_fmaf(h5, W1[5], s11);
            s00 = __builtin_fmaf(h6, W0[6], s00);  s01 = __builtin_fmaf(h7, W0[7], s01);
            s10 = __builtin_fmaf(h6, W1[6], s10);  s11 = __builtin_fmaf(h7, W1[7], s11);
            const float pre0 = s00 + s01;          // already scaled
            const float pre1 = s10 + s11;

            // ---- activations (two independent trans chains)
            const float e0 = __builtin_amdgcn_exp2f(pre0);
            const float e1 = __builtin_amdgcn_exp2f(pre1);
            const float r0 = __builtin_amdgcn_rcpf(e0 + 1.0f);
            const float r1 = __builtin_amdgcn_rcpf(e1 + 1.0f);
            const float a0 = r0 * tm0;                        // gi | gf
            const float a1 = __builtin_fmaf(r1, 2.0f, addc1); // gg | go2

            // ---- local product + 3 bank-masked ror8 exchanges
            const float pp  = a0 * a1;                 // half0: gi*gg
            const float gf  = ror8_keep<0x3>(a0, a0);  // all lanes: sigma_f
            const float go2 = ror8_keep<0x3>(a1, a1);  // all lanes: 2*sigma_o
            const float ig  = ror8_keep<0xC>(pp, pp);  // all lanes: gi*gg

            // ---- c/h update, valid in ALL lanes (h replicated by constr.)
            c = __builtin_fmaf(gf, c, ig);             // scaled-c recurrence
            const float e2 = __builtin_amdgcn_exp2f(c);
            const float r2 = __builtin_amdgcn_rcpf(e2 + 1.0f);
            h = __builtin_fmaf(go2, r2, go2 * -0.5f);  // h = 2sig*r - sig
        }
    }

    if (!hf) out[b * 8 + u] = h;
}

extern "C" void kernel_launch(void* const* d_in, const int* in_sizes, int n_in,
                              void* d_out, int out_size, void* d_ws, size_t ws_size,
                              hipStream_t stream) {
    const float* x   = (const float*)d_in[0];
    const float* h0  = (const float*)d_in[1];
    const float* c0  = (const float*)d_in[2];
    const float* Wih = (const float*)d_in[3];
    const float* Whh = (const float*)d_in[4];
    const float* bih = (const float*)d_in[5];
    const float* bhh = (const float*)d_in[6];
    float* out = (float*)d_out;

    dim3 grid(BATCH / 16);   // 256 blocks
    dim3 block(256);         // 16 groups of 16 lanes; 1024 waves = 1/SIMD
    hipLaunchKernelGGL(lstm_kernel, grid, block, 0, stream,
                       x, h0, c0, Wih, Whh, bih, bhh, out);
}